// Round 1
// baseline (1657.418 us; speedup 1.0000x reference)
//
#include <hip/hip_runtime.h>
#include <math.h>

// Plan (fp32 correctness-first baseline):
//  1. wd  = wq - wk   (q2-k2 = gf2 @ wd)   ; wd2 = wq2 - wk2 (q1-k1 = xg @ wd2)
//  2. x   = features @ fc1_w + fc1_b                       [GEMM 16384x1024x64]
//  3. e1  = exp(mlp_chain_128(x_groups) * 1/sqrt(128))     [fused chain kernel]
//  4. cs1 = column sums of e1 (softmax denominator, no max-sub: inputs ~1e-2)
//  5. d2  = x[14336:,:] @ wd ; t2 = relu(d2@g1_w+b) ; e2 = exp((t2@g2_w+b)/32)
//  6. cs2 = column sums of e2
//  7. v   = x @ wv                                         [GEMM 16384x1024x1024]
//  8. epilogue: res = (e1/cs1 + e2[n&2047]/cs2) * (v + pe0(features[:,0]))
//              out = res @ fc2_w + fc2_b + features
// Workspace: ~220 MB fp32.

__global__ void zero_k(float* __restrict__ p, int n) {
    int i = blockIdx.x * 256 + threadIdx.x;
    if (i < n) p[i] = 0.f;
}

__global__ void sub_k(const float* __restrict__ a, const float* __restrict__ b,
                      float* __restrict__ o, int n) {
    int i = blockIdx.x * 256 + threadIdx.x;
    if (i < n) o[i] = a[i] - b[i];
}

// C[M,N] = op(A[M,K] @ W[K,N] + bias); OP: 0 none, 1 relu, 2 exp(x*scale)
// 64x64 tile, 256 threads, 4x4 micro-tile. M,N,K all divisible by 64/16 here.
template <int OP>
__global__ __launch_bounds__(256) void gemm_f32(
    const float* __restrict__ A, const float* __restrict__ W,
    const float* __restrict__ bias, float* __restrict__ Co,
    int M, int Nn, int K, float scale)
{
    __shared__ float As[16][68];  // [k][m], +4 pad: 16B-aligned rows, few conflicts
    __shared__ float Ws[16][68];  // [k][n]
    const int tid = threadIdx.x;
    const int bm = blockIdx.y << 6, bn = blockIdx.x << 6;
    const int tm = (tid >> 4) << 2;
    const int tn = (tid & 15) << 2;
    float acc[4][4] = {};
    for (int k0 = 0; k0 < K; k0 += 16) {
        #pragma unroll
        for (int i = 0; i < 4; ++i) {
            int idx = tid + i * 256;          // 0..1023
            int m = idx >> 4, k = idx & 15;
            As[k][m] = A[(long)(bm + m) * K + k0 + k];
        }
        #pragma unroll
        for (int i = 0; i < 4; ++i) {
            int idx = tid + i * 256;
            int k = idx >> 6, n = idx & 63;
            Ws[k][n] = W[(long)(k0 + k) * Nn + bn + n];
        }
        __syncthreads();
        #pragma unroll
        for (int k = 0; k < 16; ++k) {
            float a0 = As[k][tm], a1 = As[k][tm + 1], a2 = As[k][tm + 2], a3 = As[k][tm + 3];
            float b0 = Ws[k][tn], b1 = Ws[k][tn + 1], b2 = Ws[k][tn + 2], b3 = Ws[k][tn + 3];
            acc[0][0] += a0 * b0; acc[0][1] += a0 * b1; acc[0][2] += a0 * b2; acc[0][3] += a0 * b3;
            acc[1][0] += a1 * b0; acc[1][1] += a1 * b1; acc[1][2] += a1 * b2; acc[1][3] += a1 * b3;
            acc[2][0] += a2 * b0; acc[2][1] += a2 * b1; acc[2][2] += a2 * b2; acc[2][3] += a2 * b3;
            acc[3][0] += a3 * b0; acc[3][1] += a3 * b1; acc[3][2] += a3 * b2; acc[3][3] += a3 * b3;
        }
        __syncthreads();
    }
    #pragma unroll
    for (int i = 0; i < 4; ++i) {
        #pragma unroll
        for (int j = 0; j < 4; ++j) {
            float cv = acc[i][j];
            if (bias) cv += bias[bn + tn + j];
            if (OP == 1) cv = fmaxf(cv, 0.f);
            if (OP == 2) cv = expf(cv * scale);
            Co[(long)(bm + tm + i) * Nn + bn + tn + j] = cv;
        }
    }
}

// Fused group-MLP chain: rows of X2 = x viewed as (N*8, 128).
// d = X2 @ wd2 ; t = relu(d @ gg1_w + gg1_b) ; h = t @ gg2_w + gg2_b
// e1 = exp(h / sqrt(128)).  Block: 32 rows. Weights staged in 64-row halves.
__global__ __launch_bounds__(256) void group_chain_k(
    const float* __restrict__ x, const float* __restrict__ wd2,
    const float* __restrict__ gg1_w, const float* __restrict__ gg1_b,
    const float* __restrict__ gg2_w, const float* __restrict__ gg2_b,
    float* __restrict__ e1)
{
    __shared__ float Wh[64 * 128];   // 32 KB: half of a 128x128 weight
    __shared__ float buf[32 * 128];  // 16 KB: current activations (in-place chain)
    const int tid = threadIdx.x;
    const long base = (long)blockIdx.x * (32 * 128);
    for (int i = tid; i < 32 * 128; i += 256) buf[i] = x[base + i];
    const int r = tid >> 3;            // 0..31
    const int c = (tid & 7) * 16;      // columns c..c+15
    float acc[16];
    const float* Wg[3] = {wd2, gg1_w, gg2_w};
    for (int s = 0; s < 3; ++s) {
        const float* W = Wg[s];
        #pragma unroll
        for (int j = 0; j < 16; ++j) acc[j] = 0.f;
        for (int kp = 0; kp < 2; ++kp) {
            __syncthreads();  // prev Wh reads done / buf writes visible
            for (int i = tid; i < 64 * 128; i += 256) Wh[i] = W[kp * 64 * 128 + i];
            __syncthreads();
            for (int k = 0; k < 64; ++k) {
                float xv = buf[r * 128 + kp * 64 + k];
                #pragma unroll
                for (int j = 0; j < 16; ++j) acc[j] += xv * Wh[k * 128 + c + j];
            }
        }
        __syncthreads();  // all reads of buf done -> safe to overwrite in place
        if (s == 0) {
            #pragma unroll
            for (int j = 0; j < 16; ++j) buf[r * 128 + c + j] = acc[j];
        } else if (s == 1) {
            #pragma unroll
            for (int j = 0; j < 16; ++j)
                buf[r * 128 + c + j] = fmaxf(acc[j] + gg1_b[c + j], 0.f);
        } else {
            #pragma unroll
            for (int j = 0; j < 16; ++j)
                buf[r * 128 + c + j] =
                    expf((acc[j] + gg2_b[c + j]) * 0.08838834764831845f);  // 1/sqrt(128)
        }
    }
    __syncthreads();
    for (int i = tid; i < 32 * 128; i += 256) e1[base + i] = buf[i];
}

// Column sums of e (M x 1024) into colsum[1024] via per-block partials + atomics.
__global__ void colsum_k(const float* __restrict__ e, float* __restrict__ colsum,
                         int M, int Nn)
{
    const int c = blockIdx.x * 64 + threadIdx.x;
    const int chunk = M / gridDim.y;
    const int r0 = blockIdx.y * chunk;
    float s = 0.f;
    for (int r = r0 + threadIdx.y; r < r0 + chunk; r += 4)
        s += e[(long)r * Nn + c];
    __shared__ float red[4][64];
    red[threadIdx.y][threadIdx.x] = s;
    __syncthreads();
    if (threadIdx.y == 0)
        atomicAdd(&colsum[c],
                  red[0][threadIdx.x] + red[1][threadIdx.x] +
                  red[2][threadIdx.x] + red[3][threadIdx.x]);
}

// Epilogue: res = (e1/cs1 + e2[n&2047]/cs2) * (v + pe0); out = res@fc2_w + fc2_b + features
constexpr int EP_ROWS = 8;
__global__ __launch_bounds__(256) void epilogue_k(
    const float* __restrict__ e1, const float* __restrict__ e2,
    const float* __restrict__ cs1, const float* __restrict__ cs2,
    const float* __restrict__ v, const float* __restrict__ feat,
    const float* __restrict__ fc2_w, const float* __restrict__ fc2_b,
    const float* __restrict__ lpe, float* __restrict__ out)
{
    __shared__ float res[EP_ROWS][1024];
    __shared__ float part[4][EP_ROWS][64];
    const int n0 = blockIdx.x * EP_ROWS;
    const float lp = lpe[0];
    for (int idx = threadIdx.x; idx < EP_ROWS * 1024; idx += 256) {
        int rr = idx >> 10;
        int h = idx & 1023;
        int n = n0 + rr;
        int hp = h & 511;
        // dim_embed = 1000^(hp/512); log2(1000) = 9.96578428466209
        float de = exp2f(9.96578428466209f * (float)hp * (1.0f / 512.0f));
        float f0 = feat[(long)n * 64];
        float ang = 100.0f * f0 / de;
        float scv = (h < 512) ? sinf(ang) : cosf(ang);
        float pe = (scv + lp) * lp;
        float a = e1[(long)n * 1024 + h] / cs1[h] +
                  e2[(long)(n & 2047) * 1024 + h] / cs2[h];
        res[rr][h] = a * (v[(long)n * 1024 + h] + pe);
    }
    __syncthreads();
    const int tx = threadIdx.x & 63, ty = threadIdx.x >> 6;
    float s[EP_ROWS];
    #pragma unroll
    for (int rr = 0; rr < EP_ROWS; ++rr) s[rr] = 0.f;
    for (int h = ty * 256; h < ty * 256 + 256; ++h) {
        float w = fc2_w[h * 64 + tx];
        #pragma unroll
        for (int rr = 0; rr < EP_ROWS; ++rr) s[rr] += res[rr][h] * w;
    }
    #pragma unroll
    for (int rr = 0; rr < EP_ROWS; ++rr) part[ty][rr][tx] = s[rr];
    __syncthreads();
    for (int idx = threadIdx.x; idx < EP_ROWS * 64; idx += 256) {
        int rr = idx >> 6, cc = idx & 63;
        float tot = part[0][rr][cc] + part[1][rr][cc] + part[2][rr][cc] + part[3][rr][cc];
        int n = n0 + rr;
        out[(long)n * 64 + cc] = tot + fc2_b[cc] + feat[(long)n * 64 + cc];
    }
}

extern "C" void kernel_launch(void* const* d_in, const int* in_sizes, int n_in,
                              void* d_out, int out_size, void* d_ws, size_t ws_size,
                              hipStream_t stream) {
    const float* features = (const float*)d_in[0];
    const float* fc1_w = (const float*)d_in[1];
    const float* fc1_b = (const float*)d_in[2];
    const float* fc2_w = (const float*)d_in[3];
    const float* fc2_b = (const float*)d_in[4];
    const float* g1_w = (const float*)d_in[5];
    const float* g1_b = (const float*)d_in[6];
    const float* g2_w = (const float*)d_in[7];
    const float* g2_b = (const float*)d_in[8];
    const float* gg1_w = (const float*)d_in[9];
    const float* gg1_b = (const float*)d_in[10];
    const float* gg2_w = (const float*)d_in[11];
    const float* gg2_b = (const float*)d_in[12];
    const float* wq = (const float*)d_in[13];
    const float* wk = (const float*)d_in[14];
    const float* wv = (const float*)d_in[15];
    const float* wq2 = (const float*)d_in[16];
    const float* wk2 = (const float*)d_in[17];
    const float* lpe = (const float*)d_in[18];
    float* out = (float*)d_out;

    float* ws = (float*)d_ws;
    float* x   = ws;
    float* e1  = x + (size_t)16384 * 1024;
    float* v   = e1 + (size_t)16384 * 1024;
    float* d2b = v + (size_t)16384 * 1024;
    float* t2b = d2b + (size_t)2048 * 1024;
    float* e2b = t2b + (size_t)2048 * 1024;
    float* wd  = e2b + (size_t)2048 * 1024;
    float* wd2 = wd + (size_t)1024 * 1024;
    float* cs1 = wd2 + 128 * 128;
    float* cs2 = cs1 + 1024;

    zero_k<<<8, 256, 0, stream>>>(cs1, 2048);
    sub_k<<<4096, 256, 0, stream>>>(wq, wk, wd, 1024 * 1024);
    sub_k<<<64, 256, 0, stream>>>(wq2, wk2, wd2, 128 * 128);

    // x = features @ fc1_w + fc1_b
    gemm_f32<0><<<dim3(16, 256), 256, 0, stream>>>(features, fc1_w, fc1_b, x,
                                                   16384, 1024, 64, 0.f);
    // group branch -> e1, cs1
    group_chain_k<<<4096, 256, 0, stream>>>(x, wd2, gg1_w, gg1_b, gg2_w, gg2_b, e1);
    colsum_k<<<dim3(16, 64), dim3(64, 4), 0, stream>>>(e1, cs1, 16384, 1024);
    // tail branch -> e2, cs2
    gemm_f32<0><<<dim3(16, 32), 256, 0, stream>>>(x + (size_t)14336 * 1024, wd, nullptr,
                                                  d2b, 2048, 1024, 1024, 0.f);
    gemm_f32<1><<<dim3(16, 32), 256, 0, stream>>>(d2b, g1_w, g1_b, t2b,
                                                  2048, 1024, 1024, 0.f);
    gemm_f32<2><<<dim3(16, 32), 256, 0, stream>>>(t2b, g2_w, g2_b, e2b,
                                                  2048, 1024, 1024, 0.03125f); // 1/sqrt(1024)
    colsum_k<<<dim3(16, 8), dim3(64, 4), 0, stream>>>(e2b, cs2, 2048, 1024);
    // v = x @ wv
    gemm_f32<0><<<dim3(16, 256), 256, 0, stream>>>(x, wv, nullptr, v,
                                                   16384, 1024, 1024, 0.f);
    // fused epilogue
    epilogue_k<<<2048, 256, 0, stream>>>(e1, e2b, cs1, cs2, v, features,
                                         fc2_w, fc2_b, lpe, out);
}

// Round 2
// 476.736 us; speedup vs baseline: 3.4766x; 3.4766x over previous
//
#include <hip/hip_runtime.h>
#include <hip/hip_bf16.h>
#include <math.h>
#include <type_traits>

// Round 2: all GEMMs -> bf16 MFMA (m97 structure: 128x128 tile, BK=32,
// global_load_lds width-16, 16x16x32 MFMA, 4 waves x 4x4 frags).
// Weights pre-transposed to [N][K] bf16 (fused with wq-wk / wq2-wk2 subtract)
// so both A and B fragment ds_reads are contiguous b128.
// Numerics: all GEMM contributions to the output are ~1e-4 absolute; bf16 safe.

typedef __attribute__((ext_vector_type(8))) short short8;
typedef __attribute__((ext_vector_type(4))) float f32x4;

#define GLOAD_LDS16(gptr, lptr)                                                 \
    __builtin_amdgcn_global_load_lds(                                           \
        (const __attribute__((address_space(1))) void*)(gptr),                  \
        (__attribute__((address_space(3))) void*)(lptr), 16, 0, 0)

__global__ void zero_k(float* __restrict__ p, int n) {
    int i = blockIdx.x * 256 + threadIdx.x;
    if (i < n) p[i] = 0.f;
}

// elementwise fp32 -> bf16
__global__ void conv_k(const float* __restrict__ in, __hip_bfloat16* __restrict__ out, int n) {
    int i = blockIdx.x * 256 + threadIdx.x;
    if (i < n) out[i] = __float2bfloat16(in[i]);
}

// transpose + convert: A[K][N] fp32 (optionally minus Bsub) -> Ot[N][K] bf16
__global__ __launch_bounds__(256) void conv_t_k(
    const float* __restrict__ A, const float* __restrict__ Bsub,
    __hip_bfloat16* __restrict__ Ot, int K, int N)
{
    __shared__ float t[32][33];
    const int n0 = blockIdx.x * 32, k0 = blockIdx.y * 32;
    const int tx = threadIdx.x, ty = threadIdx.y;  // (32,8)
    #pragma unroll
    for (int j = 0; j < 4; ++j) {
        int k = k0 + ty + j * 8;
        float v = A[(long)k * N + n0 + tx];
        if (Bsub) v -= Bsub[(long)k * N + n0 + tx];
        t[ty + j * 8][tx] = v;
    }
    __syncthreads();
    #pragma unroll
    for (int j = 0; j < 4; ++j) {
        int n = n0 + ty + j * 8;
        Ot[(long)n * K + k0 + tx] = __float2bfloat16(t[tx][ty + j * 8]);
    }
}

// C[M,N] = op(A[M,K] @ B[K,N] + bias), A row-major bf16, Bt = B^T [N][K] bf16.
// OP: 0 none, 1 relu, 2 exp(x*scale). OutT: __hip_bfloat16 or float.
// M%128==0, N%128==0, K%32==0.
template <int OP, typename OutT>
__global__ __launch_bounds__(256) void gemm_bf16(
    const __hip_bfloat16* __restrict__ A, const __hip_bfloat16* __restrict__ Bt,
    const float* __restrict__ bias, OutT* __restrict__ Co,
    int M, int Nn, int K, float scale)
{
    __shared__ __hip_bfloat16 As[128 * 32];  // [m][k] linear
    __shared__ __hip_bfloat16 Bs[128 * 32];  // [n][k] linear
    const int tid = threadIdx.x;
    const int wid = tid >> 6;
    const int lane = tid & 63;
    const int bm = blockIdx.y << 7, bn = blockIdx.x << 7;
    const int wm = (wid >> 1) << 6, wn = (wid & 1) << 6;  // wave 64x64 sub-tile

    f32x4 acc[4][4] = {};  // acc[m][n], one 16x16 frag each

    // staging index: idx in [0,512): r = idx>>2 (row), c = (idx&3)*8 (k elem)
    const int idx0 = tid, idx1 = tid + 256;
    const int r0 = idx0 >> 2, c0 = (idx0 & 3) << 3;
    const int r1 = idx1 >> 2, c1 = (idx1 & 3) << 3;
    // wave-uniform LDS bases (bytes = elem*2); lane l lands at base + l*16
    __hip_bfloat16* lA0 = As + (size_t)(0 * 256 + (wid << 6)) * 8;
    __hip_bfloat16* lA1 = As + (size_t)(1 * 256 + (wid << 6)) * 8;
    __hip_bfloat16* lB0 = Bs + (size_t)(0 * 256 + (wid << 6)) * 8;
    __hip_bfloat16* lB1 = Bs + (size_t)(1 * 256 + (wid << 6)) * 8;

    const int arow = wm + (lane & 15);
    const int brow = wn + (lane & 15);
    const int kg = lane >> 4;

    for (int k0 = 0; k0 < K; k0 += 32) {
        GLOAD_LDS16(A + (long)(bm + r0) * K + k0 + c0, lA0);
        GLOAD_LDS16(A + (long)(bm + r1) * K + k0 + c1, lA1);
        GLOAD_LDS16(Bt + (long)(bn + r0) * K + k0 + c0, lB0);
        GLOAD_LDS16(Bt + (long)(bn + r1) * K + k0 + c1, lB1);
        __syncthreads();  // compiler drains vmcnt before s_barrier

        short8 af[4], bf_[4];
        #pragma unroll
        for (int m = 0; m < 4; ++m)
            af[m] = ((const short8*)As)[(arow + m * 16) * 4 + kg];
        #pragma unroll
        for (int n = 0; n < 4; ++n)
            bf_[n] = ((const short8*)Bs)[(brow + n * 16) * 4 + kg];
        #pragma unroll
        for (int m = 0; m < 4; ++m)
            #pragma unroll
            for (int n = 0; n < 4; ++n)
                acc[m][n] = __builtin_amdgcn_mfma_f32_16x16x32_bf16(
                    af[m], bf_[n], acc[m][n], 0, 0, 0);
        __syncthreads();  // all frag reads done before next stage overwrites
    }

    // C/D layout: col = lane&15, row = (lane>>4)*4 + reg  [m89/m91 verified]
    const int rq = (lane >> 4) << 2;
    #pragma unroll
    for (int n = 0; n < 4; ++n) {
        const int col = bn + wn + n * 16 + (lane & 15);
        const float bv = bias ? bias[col] : 0.f;
        #pragma unroll
        for (int m = 0; m < 4; ++m) {
            #pragma unroll
            for (int j = 0; j < 4; ++j) {
                const int row = bm + wm + m * 16 + rq + j;
                float cv = acc[m][n][j] + bv;
                if (OP == 1) cv = fmaxf(cv, 0.f);
                if (OP == 2) cv = expf(cv * scale);
                if constexpr (std::is_same<OutT, float>::value)
                    Co[(long)row * Nn + col] = cv;
                else
                    Co[(long)row * Nn + col] = __float2bfloat16(cv);
            }
        }
    }
}

// Column sums of e (M x 1024 fp32) into colsum via per-block partials + atomics.
__global__ void colsum_k(const float* __restrict__ e, float* __restrict__ colsum,
                         int M, int Nn)
{
    const int c = blockIdx.x * 64 + threadIdx.x;
    const int chunk = M / gridDim.y;
    const int r0 = blockIdx.y * chunk;
    float s = 0.f;
    for (int r = r0 + threadIdx.y; r < r0 + chunk; r += 4)
        s += e[(long)r * Nn + c];
    __shared__ float red[4][64];
    red[threadIdx.y][threadIdx.x] = s;
    __syncthreads();
    if (threadIdx.y == 0)
        atomicAdd(&colsum[c],
                  red[0][threadIdx.x] + red[1][threadIdx.x] +
                  red[2][threadIdx.x] + red[3][threadIdx.x]);
}

// Epilogue: res = (e1/cs1 + e2[n&2047]/cs2) * (v + pe0); out = res@fc2_w + fc2_b + feat
constexpr int EP_ROWS = 8;
__global__ __launch_bounds__(256) void epilogue_k(
    const float* __restrict__ e1, const float* __restrict__ e2,
    const float* __restrict__ cs1, const float* __restrict__ cs2,
    const __hip_bfloat16* __restrict__ v, const float* __restrict__ feat,
    const float* __restrict__ fc2_w, const float* __restrict__ fc2_b,
    const float* __restrict__ lpe, float* __restrict__ out)
{
    __shared__ float res[EP_ROWS][1024];
    __shared__ float part[4][EP_ROWS][64];
    const int n0 = blockIdx.x * EP_ROWS;
    const float lp = lpe[0];
    for (int idx = threadIdx.x; idx < EP_ROWS * 1024; idx += 256) {
        int rr = idx >> 10;
        int h = idx & 1023;
        int n = n0 + rr;
        int hp = h & 511;
        // dim_embed = 1000^(hp/512); log2(1000) = 9.96578428466209
        float de = exp2f(9.96578428466209f * (float)hp * (1.0f / 512.0f));
        float f0 = feat[(long)n * 64];
        float ang = 100.0f * f0 / de;
        float scv = (h < 512) ? sinf(ang) : cosf(ang);
        float pe = (scv + lp) * lp;
        float a = e1[(long)n * 1024 + h] / cs1[h] +
                  e2[(long)(n & 2047) * 1024 + h] / cs2[h];
        res[rr][h] = a * (__bfloat162float(v[(long)n * 1024 + h]) + pe);
    }
    __syncthreads();
    const int tx = threadIdx.x & 63, ty = threadIdx.x >> 6;
    float s[EP_ROWS];
    #pragma unroll
    for (int rr = 0; rr < EP_ROWS; ++rr) s[rr] = 0.f;
    for (int h = ty * 256; h < ty * 256 + 256; ++h) {
        float w = fc2_w[h * 64 + tx];
        #pragma unroll
        for (int rr = 0; rr < EP_ROWS; ++rr) s[rr] += res[rr][h] * w;
    }
    #pragma unroll
    for (int rr = 0; rr < EP_ROWS; ++rr) part[ty][rr][tx] = s[rr];
    __syncthreads();
    for (int idx = threadIdx.x; idx < EP_ROWS * 64; idx += 256) {
        int rr = idx >> 6, cc = idx & 63;
        float tot = part[0][rr][cc] + part[1][rr][cc] + part[2][rr][cc] + part[3][rr][cc];
        int n = n0 + rr;
        out[(long)n * 64 + cc] = tot + fc2_b[cc] + feat[(long)n * 64 + cc];
    }
}

extern "C" void kernel_launch(void* const* d_in, const int* in_sizes, int n_in,
                              void* d_out, int out_size, void* d_ws, size_t ws_size,
                              hipStream_t stream) {
    const float* features = (const float*)d_in[0];
    const float* fc1_w = (const float*)d_in[1];
    const float* fc1_b = (const float*)d_in[2];
    const float* fc2_w = (const float*)d_in[3];
    const float* fc2_b = (const float*)d_in[4];
    const float* g1_w = (const float*)d_in[5];
    const float* g1_b = (const float*)d_in[6];
    const float* g2_w = (const float*)d_in[7];
    const float* g2_b = (const float*)d_in[8];
    const float* gg1_w = (const float*)d_in[9];
    const float* gg1_b = (const float*)d_in[10];
    const float* gg2_w = (const float*)d_in[11];
    const float* gg2_b = (const float*)d_in[12];
    const float* wq = (const float*)d_in[13];
    const float* wk = (const float*)d_in[14];
    const float* wv = (const float*)d_in[15];
    const float* wq2 = (const float*)d_in[16];
    const float* wk2 = (const float*)d_in[17];
    const float* lpe = (const float*)d_in[18];
    float* out = (float*)d_out;

    // workspace layout (bytes)
    char* ws = (char*)d_ws;
    const size_t MB = 1024ull * 1024ull;
    __hip_bfloat16* xb  = (__hip_bfloat16*)ws;                  // 32 MB  x bf16 (16384x1024)
    float*          e1  = (float*)(ws + 32 * MB);               // 64 MB
    __hip_bfloat16* vb  = (__hip_bfloat16*)(ws + 96 * MB);      // 32 MB  v bf16; also d1b (dead before v-GEMM)
    __hip_bfloat16* d1b = vb;
    char* D = ws + 128 * MB;                                    // 32 MB region
    __hip_bfloat16* t1b = (__hip_bfloat16*)D;                   // 32 MB (dead before tail)
    __hip_bfloat16* d2b = (__hip_bfloat16*)D;                   // 4 MB
    __hip_bfloat16* t2b = (__hip_bfloat16*)(D + 4 * MB);        // 4 MB
    float*          e2b = (float*)(D + 8 * MB);                 // 8 MB
    char* W = ws + 160 * MB;
    __hip_bfloat16* featb = (__hip_bfloat16*)W;                 // 2 MB (16384x64)
    __hip_bfloat16* fc1T  = (__hip_bfloat16*)(W + 2 * MB);      // 128 KB (1024x64)
    __hip_bfloat16* wdT   = (__hip_bfloat16*)(W + 3 * MB);      // 2 MB (1024x1024)
    __hip_bfloat16* wvT   = (__hip_bfloat16*)(W + 5 * MB);      // 2 MB
    __hip_bfloat16* g1T   = (__hip_bfloat16*)(W + 7 * MB);      // 2 MB
    __hip_bfloat16* g2T   = (__hip_bfloat16*)(W + 9 * MB);      // 2 MB
    __hip_bfloat16* wd2T  = (__hip_bfloat16*)(W + 11 * MB);     // 32 KB (128x128)
    __hip_bfloat16* gg1T  = (__hip_bfloat16*)(W + 11 * MB + 64 * 1024);
    __hip_bfloat16* gg2T  = (__hip_bfloat16*)(W + 11 * MB + 128 * 1024);
    float* cs1 = (float*)(W + 12 * MB);                         // 4 KB
    float* cs2 = cs1 + 1024;

    zero_k<<<8, 256, 0, stream>>>(cs1, 2048);
    conv_k<<<4096, 256, 0, stream>>>(features, featb, 16384 * 64);
    conv_t_k<<<dim3(32, 2),  dim3(32, 8), 0, stream>>>(fc1_w, nullptr, fc1T, 64, 1024);
    conv_t_k<<<dim3(32, 32), dim3(32, 8), 0, stream>>>(wq, wk, wdT, 1024, 1024);
    conv_t_k<<<dim3(32, 32), dim3(32, 8), 0, stream>>>(wv, nullptr, wvT, 1024, 1024);
    conv_t_k<<<dim3(32, 32), dim3(32, 8), 0, stream>>>(g1_w, nullptr, g1T, 1024, 1024);
    conv_t_k<<<dim3(32, 32), dim3(32, 8), 0, stream>>>(g2_w, nullptr, g2T, 1024, 1024);
    conv_t_k<<<dim3(4, 4),   dim3(32, 8), 0, stream>>>(wq2, wk2, wd2T, 128, 128);
    conv_t_k<<<dim3(4, 4),   dim3(32, 8), 0, stream>>>(gg1_w, nullptr, gg1T, 128, 128);
    conv_t_k<<<dim3(4, 4),   dim3(32, 8), 0, stream>>>(gg2_w, nullptr, gg2T, 128, 128);

    // x = features @ fc1_w + fc1_b   (16384x1024x64) -> bf16
    gemm_bf16<0, __hip_bfloat16><<<dim3(8, 128), 256, 0, stream>>>(
        featb, fc1T, fc1_b, xb, 16384, 1024, 64, 0.f);

    // group branch: flat (131072x128) chain -> e1 fp32
    gemm_bf16<0, __hip_bfloat16><<<dim3(1, 1024), 256, 0, stream>>>(
        xb, wd2T, nullptr, d1b, 131072, 128, 128, 0.f);
    gemm_bf16<1, __hip_bfloat16><<<dim3(1, 1024), 256, 0, stream>>>(
        d1b, gg1T, gg1_b, t1b, 131072, 128, 128, 0.f);
    gemm_bf16<2, float><<<dim3(1, 1024), 256, 0, stream>>>(
        t1b, gg2T, gg2_b, e1, 131072, 128, 128, 0.08838834764831845f); // 1/sqrt(128)
    colsum_k<<<dim3(16, 64), dim3(64, 4), 0, stream>>>(e1, cs1, 16384, 1024);

    // tail branch: (2048x1024x1024) chain -> e2 fp32
    gemm_bf16<0, __hip_bfloat16><<<dim3(8, 16), 256, 0, stream>>>(
        xb + (size_t)14336 * 1024, wdT, nullptr, d2b, 2048, 1024, 1024, 0.f);
    gemm_bf16<1, __hip_bfloat16><<<dim3(8, 16), 256, 0, stream>>>(
        d2b, g1T, g1_b, t2b, 2048, 1024, 1024, 0.f);
    gemm_bf16<2, float><<<dim3(8, 16), 256, 0, stream>>>(
        t2b, g2T, g2_b, e2b, 2048, 1024, 1024, 0.03125f); // 1/sqrt(1024)
    colsum_k<<<dim3(16, 8), dim3(64, 4), 0, stream>>>(e2b, cs2, 2048, 1024);

    // v = x @ wv -> bf16
    gemm_bf16<0, __hip_bfloat16><<<dim3(8, 128), 256, 0, stream>>>(
        xb, wvT, nullptr, vb, 16384, 1024, 1024, 0.f);

    // fused epilogue
    epilogue_k<<<2048, 256, 0, stream>>>(e1, e2b, cs1, cs2, vb, features,
                                         fc2_w, fc2_b, lpe, out);
}

// Round 3
// 398.948 us; speedup vs baseline: 4.1545x; 1.1950x over previous
//
#include <hip/hip_runtime.h>
#include <hip/hip_bf16.h>
#include <math.h>
#include <type_traits>

// Round 3:
//  - chain_k: fused group-MLP (3x 128x128 MFMA stages in-place in LDS, XOR-swizzled,
//    weights streamed, cs1 colsum fused via atomics). Replaces 3 GEMMs + colsum.
//  - gemm_v_res: v = x@wv with fused attn/PE/res epilogue (native trig, reciprocal
//    multiplies). Replaces v-GEMM + epilogue elementwise phase; v never hits HBM.
//  - out_gemm_k: out = res@fc2_w + fc2_b + features (MFMA, M-tile 64).
//  - e1/e2 stored bf16.

typedef __attribute__((ext_vector_type(8))) short short8;
typedef __attribute__((ext_vector_type(4))) float f32x4;

#define GLOAD_LDS16(gptr, lptr)                                                 \
    __builtin_amdgcn_global_load_lds(                                           \
        (const __attribute__((address_space(1))) void*)(gptr),                  \
        (__attribute__((address_space(3))) void*)(lptr), 16, 0, 0)

static __device__ __forceinline__ unsigned short f2bf_bits(float v) {
    __hip_bfloat16 h = __float2bfloat16(v);
    return __builtin_bit_cast(unsigned short, h);
}
static __device__ __forceinline__ float bf_bits2f(unsigned short u) {
    return __bfloat162float(__builtin_bit_cast(__hip_bfloat16, u));
}
// swizzled chunk index for 16B chunk (r, c16) in a [R][128-elem] bf16 tile
static __device__ __forceinline__ int swz16(int r, int c16) {
    return (r << 4) + (c16 ^ (r & 7));
}
// swizzled ushort index for element (r, c) in [R][128] bf16 tile
static __device__ __forceinline__ int swz_elem(int r, int c) {
    return (r << 7) + ((((c << 1) ^ ((r & 7) << 4))) >> 1);
}

__global__ void zero_k(float* __restrict__ p, int n) {
    int i = blockIdx.x * 256 + threadIdx.x;
    if (i < n) p[i] = 0.f;
}

__global__ void invde_k(float* __restrict__ invde) {
    int i = blockIdx.x * 256 + threadIdx.x;
    if (i < 512) invde[i] = exp2f(-9.96578428466209f * (float)i * (1.f / 512.f));
}

__global__ void rcs_k(float* __restrict__ cs, int n) {
    int i = blockIdx.x * 256 + threadIdx.x;
    if (i < n) cs[i] = 1.f / cs[i];
}

__global__ void conv_k(const float* __restrict__ in, __hip_bfloat16* __restrict__ out, int n) {
    int i = blockIdx.x * 256 + threadIdx.x;
    if (i < n) out[i] = __float2bfloat16(in[i]);
}

// transpose + convert: A[K][N] fp32 (optionally minus Bsub) -> Ot[N][K] bf16
__global__ __launch_bounds__(256) void conv_t_k(
    const float* __restrict__ A, const float* __restrict__ Bsub,
    __hip_bfloat16* __restrict__ Ot, int K, int N)
{
    __shared__ float t[32][33];
    const int n0 = blockIdx.x * 32, k0 = blockIdx.y * 32;
    const int tx = threadIdx.x, ty = threadIdx.y;  // (32,8)
    #pragma unroll
    for (int j = 0; j < 4; ++j) {
        int k = k0 + ty + j * 8;
        float v = A[(long)k * N + n0 + tx];
        if (Bsub) v -= Bsub[(long)k * N + n0 + tx];
        t[ty + j * 8][tx] = v;
    }
    __syncthreads();
    #pragma unroll
    for (int j = 0; j < 4; ++j) {
        int n = n0 + ty + j * 8;
        Ot[(long)n * K + k0 + tx] = __float2bfloat16(t[tx][ty + j * 8]);
    }
}

// ---------------- generic 128x128 MFMA GEMM (round-2 proven) ----------------
// C[M,N] = op(A[M,K] @ B + bias), Bt = B^T [N][K] bf16. OP: 0 none, 1 relu, 2 exp(x*scale)
template <int OP, typename OutT>
__global__ __launch_bounds__(256) void gemm_bf16(
    const __hip_bfloat16* __restrict__ A, const __hip_bfloat16* __restrict__ Bt,
    const float* __restrict__ bias, OutT* __restrict__ Co,
    int M, int Nn, int K, float scale)
{
    __shared__ __hip_bfloat16 As[128 * 32];
    __shared__ __hip_bfloat16 Bs[128 * 32];
    const int tid = threadIdx.x;
    const int wid = tid >> 6;
    const int lane = tid & 63;
    const int bm = blockIdx.y << 7, bn = blockIdx.x << 7;
    const int wm = (wid >> 1) << 6, wn = (wid & 1) << 6;

    f32x4 acc[4][4] = {};

    const int idx0 = tid, idx1 = tid + 256;
    const int r0 = idx0 >> 2, c0 = (idx0 & 3) << 3;
    const int r1 = idx1 >> 2, c1 = (idx1 & 3) << 3;
    __hip_bfloat16* lA0 = As + (size_t)(0 * 256 + (wid << 6)) * 8;
    __hip_bfloat16* lA1 = As + (size_t)(1 * 256 + (wid << 6)) * 8;
    __hip_bfloat16* lB0 = Bs + (size_t)(0 * 256 + (wid << 6)) * 8;
    __hip_bfloat16* lB1 = Bs + (size_t)(1 * 256 + (wid << 6)) * 8;

    const int arow = wm + (lane & 15);
    const int brow = wn + (lane & 15);
    const int kg = lane >> 4;

    for (int k0 = 0; k0 < K; k0 += 32) {
        GLOAD_LDS16(A + (long)(bm + r0) * K + k0 + c0, lA0);
        GLOAD_LDS16(A + (long)(bm + r1) * K + k0 + c1, lA1);
        GLOAD_LDS16(Bt + (long)(bn + r0) * K + k0 + c0, lB0);
        GLOAD_LDS16(Bt + (long)(bn + r1) * K + k0 + c1, lB1);
        __syncthreads();

        short8 af[4], bf_[4];
        #pragma unroll
        for (int m = 0; m < 4; ++m)
            af[m] = ((const short8*)As)[(arow + m * 16) * 4 + kg];
        #pragma unroll
        for (int n = 0; n < 4; ++n)
            bf_[n] = ((const short8*)Bs)[(brow + n * 16) * 4 + kg];
        #pragma unroll
        for (int m = 0; m < 4; ++m)
            #pragma unroll
            for (int n = 0; n < 4; ++n)
                acc[m][n] = __builtin_amdgcn_mfma_f32_16x16x32_bf16(
                    af[m], bf_[n], acc[m][n], 0, 0, 0);
        __syncthreads();
    }

    const int rq = (lane >> 4) << 2;
    #pragma unroll
    for (int n = 0; n < 4; ++n) {
        const int col = bn + wn + n * 16 + (lane & 15);
        const float bv = bias ? bias[col] : 0.f;
        #pragma unroll
        for (int m = 0; m < 4; ++m) {
            #pragma unroll
            for (int j = 0; j < 4; ++j) {
                const int row = bm + wm + m * 16 + rq + j;
                float cv = acc[m][n][j] + bv;
                if (OP == 1) cv = fmaxf(cv, 0.f);
                if (OP == 2) cv = __expf(cv * scale);
                if constexpr (std::is_same<OutT, float>::value)
                    Co[(long)row * Nn + col] = cv;
                else
                    Co[(long)row * Nn + col] = __float2bfloat16(cv);
            }
        }
    }
}

// ---------------- fused group-MLP chain ----------------
// x flat [131072][128] bf16; per block: 128 rows. In-LDS chain:
// d1 = x@w1T ; t = relu(d1@w2T + b2) ; e = exp((t@w3T + b3)/sqrt(128))
// e1 written bf16; cs1[g*128+c] += column partials (rows with flat_row&7==g).
__global__ __launch_bounds__(256) void chain_k(
    const __hip_bfloat16* __restrict__ xb,
    const __hip_bfloat16* __restrict__ w1T,
    const __hip_bfloat16* __restrict__ w2T,
    const __hip_bfloat16* __restrict__ w3T,
    const float* __restrict__ b2, const float* __restrict__ b3,
    __hip_bfloat16* __restrict__ e1, float* __restrict__ cs1)
{
    __shared__ unsigned short act[128 * 128];  // 32 KB, swizzled
    __shared__ unsigned short Wb[128 * 128];   // 32 KB, swizzled (streamed W1->W2->W3)
    const int tid = threadIdx.x, wid = tid >> 6, lane = tid & 63;
    const int wm = (wid >> 1) << 6, wn = (wid & 1) << 6;
    const long tile = (long)blockIdx.x * (128 * 128);

    // stage x -> act, W1 -> Wb (pre-swizzled global source, linear LDS dest)
    #pragma unroll
    for (int i = 0; i < 8; ++i) {
        int L = i * 256 + wid * 64 + lane;
        int r = L >> 4, c16o = (L & 15) ^ (r & 7);
        GLOAD_LDS16(xb + tile + r * 128 + c16o * 8,
                    (char*)act + (i * 256 + wid * 64) * 16);
        GLOAD_LDS16(w1T + r * 128 + c16o * 8,
                    (char*)Wb + (i * 256 + wid * 64) * 16);
    }
    __syncthreads();

    f32x4 acc[4][4];
    const int rq = (lane >> 4) << 2;

#define CHAIN_ZERO()                                                            \
    _Pragma("unroll") for (int m = 0; m < 4; ++m)                               \
        _Pragma("unroll") for (int n = 0; n < 4; ++n)                           \
            acc[m][n] = (f32x4){0.f, 0.f, 0.f, 0.f};

#define CHAIN_MM()                                                              \
    _Pragma("unroll") for (int ks = 0; ks < 4; ++ks) {                          \
        short8 af[4], bfv[4];                                                   \
        const int kc = ks * 4 + (lane >> 4);                                    \
        _Pragma("unroll") for (int m = 0; m < 4; ++m) {                         \
            int r = wm + m * 16 + (lane & 15);                                  \
            af[m] = *(const short8*)((const char*)act + swz16(r, kc) * 16);     \
        }                                                                       \
        _Pragma("unroll") for (int n = 0; n < 4; ++n) {                         \
            int r = wn + n * 16 + (lane & 15);                                  \
            bfv[n] = *(const short8*)((const char*)Wb + swz16(r, kc) * 16);     \
        }                                                                       \
        _Pragma("unroll") for (int m = 0; m < 4; ++m)                           \
            _Pragma("unroll") for (int n = 0; n < 4; ++n)                       \
                acc[m][n] = __builtin_amdgcn_mfma_f32_16x16x32_bf16(            \
                    af[m], bfv[n], acc[m][n], 0, 0, 0);                         \
    }

#define STAGE_W(wptr)                                                           \
    _Pragma("unroll") for (int i = 0; i < 8; ++i) {                             \
        int L = i * 256 + wid * 64 + lane;                                      \
        int r = L >> 4, c16o = (L & 15) ^ (r & 7);                              \
        GLOAD_LDS16((wptr) + r * 128 + c16o * 8,                                \
                    (char*)Wb + (i * 256 + wid * 64) * 16);                     \
    }

    // ---- stage 1: d1 = x @ w1T ----
    CHAIN_ZERO(); CHAIN_MM();
    __syncthreads();                 // all reads of act & Wb done
    STAGE_W(w2T);
    #pragma unroll
    for (int m = 0; m < 4; ++m)
        #pragma unroll
        for (int n = 0; n < 4; ++n)
            #pragma unroll
            for (int j = 0; j < 4; ++j) {
                int row = wm + m * 16 + rq + j, col = wn + n * 16 + (lane & 15);
                act[swz_elem(row, col)] = f2bf_bits(acc[m][n][j]);
            }
    __syncthreads();                 // drains gload vmcnt + LDS writes

    // ---- stage 2: t = relu(d1 @ w2T + b2) ----
    CHAIN_ZERO(); CHAIN_MM();
    __syncthreads();
    STAGE_W(w3T);
    {
        float bv[4];
        #pragma unroll
        for (int n = 0; n < 4; ++n) bv[n] = b2[wn + n * 16 + (lane & 15)];
        #pragma unroll
        for (int m = 0; m < 4; ++m)
            #pragma unroll
            for (int n = 0; n < 4; ++n)
                #pragma unroll
                for (int j = 0; j < 4; ++j) {
                    int row = wm + m * 16 + rq + j, col = wn + n * 16 + (lane & 15);
                    act[swz_elem(row, col)] = f2bf_bits(fmaxf(acc[m][n][j] + bv[n], 0.f));
                }
    }
    __syncthreads();

    // ---- stage 3: e = exp((t @ w3T + b3) / sqrt(128)) ----
    CHAIN_ZERO(); CHAIN_MM();
    __syncthreads();
    {
        float bv[4];
        #pragma unroll
        for (int n = 0; n < 4; ++n) bv[n] = b3[wn + n * 16 + (lane & 15)];
        #pragma unroll
        for (int m = 0; m < 4; ++m)
            #pragma unroll
            for (int n = 0; n < 4; ++n)
                #pragma unroll
                for (int j = 0; j < 4; ++j) {
                    int row = wm + m * 16 + rq + j, col = wn + n * 16 + (lane & 15);
                    float ev = __expf((acc[m][n][j] + bv[n]) * 0.08838834764831845f);
                    act[swz_elem(row, col)] = f2bf_bits(ev);
                }
    }
    __syncthreads();

    // copy act -> e1 (global, linear) : unswizzle via swizzled LDS reads
    #pragma unroll
    for (int i = 0; i < 8; ++i) {
        int idx = i * 256 + tid;
        int r = idx >> 4, c16o = idx & 15;
        short8 vd = *(const short8*)((const char*)act + swz16(r, c16o) * 16);
        *(short8*)((__hip_bfloat16*)e1 + tile + r * 128 + c16o * 8) = vd;
    }
    // cs1 partials: (g,c) pair -> sum over the 16 rows with row&7==g
    #pragma unroll
    for (int i = 0; i < 4; ++i) {
        int p = i * 256 + tid;
        int g = p >> 7, c = p & 127;
        float s = 0.f;
        #pragma unroll
        for (int t16 = 0; t16 < 16; ++t16) {
            int r = t16 * 8 + g;
            s += bf_bits2f(act[swz_elem(r, c)]);
        }
        atomicAdd(&cs1[(g << 7) + c], s);
    }
#undef CHAIN_ZERO
#undef CHAIN_MM
#undef STAGE_W
}

// ---------------- v-GEMM with fused res epilogue ----------------
// res[n][h] = (e1[n][h]*rcs1[h] + e2[n&2047][h]*rcs2[h]) * (v[n][h] + pe(n,h))
__global__ __launch_bounds__(256) void gemm_v_res(
    const __hip_bfloat16* __restrict__ A, const __hip_bfloat16* __restrict__ Bt,
    const __hip_bfloat16* __restrict__ e1, const __hip_bfloat16* __restrict__ e2,
    const float* __restrict__ rcs1, const float* __restrict__ rcs2,
    const float* __restrict__ invde, const float* __restrict__ feats,
    const float* __restrict__ lpe, __hip_bfloat16* __restrict__ res,
    int M, int Nn, int K)
{
    __shared__ __hip_bfloat16 As[128 * 32];
    __shared__ __hip_bfloat16 Bs[128 * 32];
    const int tid = threadIdx.x;
    const int wid = tid >> 6;
    const int lane = tid & 63;
    const int bm = blockIdx.y << 7, bn = blockIdx.x << 7;
    const int wm = (wid >> 1) << 6, wn = (wid & 1) << 6;

    f32x4 acc[4][4] = {};

    const int idx0 = tid, idx1 = tid + 256;
    const int r0 = idx0 >> 2, c0 = (idx0 & 3) << 3;
    const int r1 = idx1 >> 2, c1 = (idx1 & 3) << 3;
    __hip_bfloat16* lA0 = As + (size_t)(0 * 256 + (wid << 6)) * 8;
    __hip_bfloat16* lA1 = As + (size_t)(1 * 256 + (wid << 6)) * 8;
    __hip_bfloat16* lB0 = Bs + (size_t)(0 * 256 + (wid << 6)) * 8;
    __hip_bfloat16* lB1 = Bs + (size_t)(1 * 256 + (wid << 6)) * 8;

    const int arow = wm + (lane & 15);
    const int brow = wn + (lane & 15);
    const int kg = lane >> 4;

    for (int k0 = 0; k0 < K; k0 += 32) {
        GLOAD_LDS16(A + (long)(bm + r0) * K + k0 + c0, lA0);
        GLOAD_LDS16(A + (long)(bm + r1) * K + k0 + c1, lA1);
        GLOAD_LDS16(Bt + (long)(bn + r0) * K + k0 + c0, lB0);
        GLOAD_LDS16(Bt + (long)(bn + r1) * K + k0 + c1, lB1);
        __syncthreads();

        short8 af[4], bf_[4];
        #pragma unroll
        for (int m = 0; m < 4; ++m)
            af[m] = ((const short8*)As)[(arow + m * 16) * 4 + kg];
        #pragma unroll
        for (int n = 0; n < 4; ++n)
            bf_[n] = ((const short8*)Bs)[(brow + n * 16) * 4 + kg];
        #pragma unroll
        for (int m = 0; m < 4; ++m)
            #pragma unroll
            for (int n = 0; n < 4; ++n)
                acc[m][n] = __builtin_amdgcn_mfma_f32_16x16x32_bf16(
                    af[m], bf_[n], acc[m][n], 0, 0, 0);
        __syncthreads();
    }

    const float lp = lpe[0];
    const int rq = (lane >> 4) << 2;
    // hoist per-row features[:,0]
    float f0s[4][4];
    #pragma unroll
    for (int m = 0; m < 4; ++m)
        #pragma unroll
        for (int j = 0; j < 4; ++j)
            f0s[m][j] = feats[(long)(bm + wm + m * 16 + rq + j) * 64];

    #pragma unroll
    for (int n = 0; n < 4; ++n) {
        const int col = bn + wn + n * 16 + (lane & 15);
        const float rc1 = rcs1[col], rc2 = rcs2[col];
        const float ide = invde[col & 511];
        const bool isSin = col < 512;
        #pragma unroll
        for (int m = 0; m < 4; ++m) {
            #pragma unroll
            for (int j = 0; j < 4; ++j) {
                const int row = bm + wm + m * 16 + rq + j;
                float ang = 100.f * f0s[m][j] * ide;
                float tr = isSin ? __sinf(ang) : __cosf(ang);
                float a = bf_bits2f(((const unsigned short*)e1)[(long)row * 1024 + col]) * rc1
                        + bf_bits2f(((const unsigned short*)e2)[(long)(row & 2047) * 1024 + col]) * rc2;
                float rv = a * (acc[m][n][j] + (tr + lp) * lp);
                res[(long)row * 1024 + col] = __float2bfloat16(rv);
            }
        }
    }
}

// ---------------- out = res @ fc2_w + fc2_b + features ----------------
// res [16384][1024] bf16, fc2T [64][1024] bf16. Tile M=64, N=64, 256 blocks.
__global__ __launch_bounds__(256) void out_gemm_k(
    const __hip_bfloat16* __restrict__ res, const __hip_bfloat16* __restrict__ fc2T,
    const float* __restrict__ fc2_b, const float* __restrict__ feats,
    float* __restrict__ out)
{
    __shared__ unsigned short As[64 * 64];  // 8 KB swizzled ([64][64] bf16)
    __shared__ unsigned short Bs[64 * 64];
    const int tid = threadIdx.x, wid = tid >> 6, lane = tid & 63;
    const int bm = blockIdx.x << 6;
    f32x4 acc[4] = {};

    for (int k0 = 0; k0 < 1024; k0 += 64) {
        #pragma unroll
        for (int i = 0; i < 2; ++i) {
            int L = i * 256 + wid * 64 + lane;
            int r = L >> 3, c16o = (L & 7) ^ (r & 7);
            GLOAD_LDS16(res + (long)(bm + r) * 1024 + k0 + c16o * 8,
                        (char*)As + (i * 256 + wid * 64) * 16);
            GLOAD_LDS16(fc2T + (long)r * 1024 + k0 + c16o * 8,
                        (char*)Bs + (i * 256 + wid * 64) * 16);
        }
        __syncthreads();
        #pragma unroll
        for (int ks = 0; ks < 2; ++ks) {
            const int kc = ks * 4 + (lane >> 4);
            const int ar = wid * 16 + (lane & 15);
            short8 af = *(const short8*)((const char*)As + ((ar << 3) + (kc ^ (ar & 7))) * 16);
            #pragma unroll
            for (int n = 0; n < 4; ++n) {
                const int br = n * 16 + (lane & 15);
                short8 bfv = *(const short8*)((const char*)Bs + ((br << 3) + (kc ^ (br & 7))) * 16);
                acc[n] = __builtin_amdgcn_mfma_f32_16x16x32_bf16(af, bfv, acc[n], 0, 0, 0);
            }
        }
        __syncthreads();
    }
    const int rq = (lane >> 4) << 2;
    #pragma unroll
    for (int n = 0; n < 4; ++n) {
        const int col = n * 16 + (lane & 15);
        const float bv = fc2_b[col];
        #pragma unroll
        for (int j = 0; j < 4; ++j) {
            const int row = bm + wid * 16 + rq + j;
            out[(long)row * 64 + col] = acc[n][j] + bv + feats[(long)row * 64 + col];
        }
    }
}

// column sums of bf16 e [M][1024] -> colsum (atomics)
__global__ void colsum_bf_k(const __hip_bfloat16* __restrict__ e, float* __restrict__ colsum,
                            int M, int Nn)
{
    const int c = blockIdx.x * 64 + threadIdx.x;
    const int chunk = M / gridDim.y;
    const int r0 = blockIdx.y * chunk;
    float s = 0.f;
    for (int r = r0 + threadIdx.y; r < r0 + chunk; r += 4)
        s += __bfloat162float(e[(long)r * Nn + c]);
    __shared__ float red[4][64];
    red[threadIdx.y][threadIdx.x] = s;
    __syncthreads();
    if (threadIdx.y == 0)
        atomicAdd(&colsum[c],
                  red[0][threadIdx.x] + red[1][threadIdx.x] +
                  red[2][threadIdx.x] + red[3][threadIdx.x]);
}

extern "C" void kernel_launch(void* const* d_in, const int* in_sizes, int n_in,
                              void* d_out, int out_size, void* d_ws, size_t ws_size,
                              hipStream_t stream) {
    const float* features = (const float*)d_in[0];
    const float* fc1_w = (const float*)d_in[1];
    const float* fc1_b = (const float*)d_in[2];
    const float* fc2_w = (const float*)d_in[3];
    const float* fc2_b = (const float*)d_in[4];
    const float* g1_w = (const float*)d_in[5];
    const float* g1_b = (const float*)d_in[6];
    const float* g2_w = (const float*)d_in[7];
    const float* g2_b = (const float*)d_in[8];
    const float* gg1_w = (const float*)d_in[9];
    const float* gg1_b = (const float*)d_in[10];
    const float* gg2_w = (const float*)d_in[11];
    const float* gg2_b = (const float*)d_in[12];
    const float* wq = (const float*)d_in[13];
    const float* wk = (const float*)d_in[14];
    const float* wv = (const float*)d_in[15];
    const float* wq2 = (const float*)d_in[16];
    const float* wk2 = (const float*)d_in[17];
    const float* lpe = (const float*)d_in[18];
    float* out = (float*)d_out;

    char* ws = (char*)d_ws;
    const size_t MB = 1024ull * 1024ull;
    __hip_bfloat16* xb   = (__hip_bfloat16*)ws;                 // 32 MB
    __hip_bfloat16* e1   = (__hip_bfloat16*)(ws + 32 * MB);     // 32 MB
    __hip_bfloat16* resb = (__hip_bfloat16*)(ws + 64 * MB);     // 32 MB
    __hip_bfloat16* d2b  = (__hip_bfloat16*)(ws + 96 * MB);     // 4 MB
    __hip_bfloat16* t2b  = (__hip_bfloat16*)(ws + 100 * MB);    // 4 MB
    __hip_bfloat16* e2b  = (__hip_bfloat16*)(ws + 104 * MB);    // 4 MB
    char* W = ws + 112 * MB;
    __hip_bfloat16* featb = (__hip_bfloat16*)W;                 // 2 MB
    __hip_bfloat16* fc1T  = (__hip_bfloat16*)(W + 2 * MB);      // 128 KB
    __hip_bfloat16* wdT   = (__hip_bfloat16*)(W + 3 * MB);      // 2 MB
    __hip_bfloat16* wvT   = (__hip_bfloat16*)(W + 5 * MB);      // 2 MB
    __hip_bfloat16* g1T   = (__hip_bfloat16*)(W + 7 * MB);      // 2 MB
    __hip_bfloat16* g2T   = (__hip_bfloat16*)(W + 9 * MB);      // 2 MB
    __hip_bfloat16* fc2T  = (__hip_bfloat16*)(W + 11 * MB);     // 128 KB
    __hip_bfloat16* wd2T  = (__hip_bfloat16*)(W + 12 * MB);     // 32 KB
    __hip_bfloat16* gg1T  = (__hip_bfloat16*)(W + 12 * MB + 64 * 1024);
    __hip_bfloat16* gg2T  = (__hip_bfloat16*)(W + 12 * MB + 128 * 1024);
    float* cs1   = (float*)(W + 13 * MB);                       // 4 KB
    float* cs2   = cs1 + 1024;
    float* invde = cs2 + 1024;                                  // 512

    zero_k<<<8, 256, 0, stream>>>(cs1, 2048);
    invde_k<<<2, 256, 0, stream>>>(invde);
    conv_k<<<4096, 256, 0, stream>>>(features, featb, 16384 * 64);
    conv_t_k<<<dim3(32, 2),  dim3(32, 8), 0, stream>>>(fc1_w, nullptr, fc1T, 64, 1024);
    conv_t_k<<<dim3(32, 32), dim3(32, 8), 0, stream>>>(wq, wk, wdT, 1024, 1024);
    conv_t_k<<<dim3(32, 32), dim3(32, 8), 0, stream>>>(wv, nullptr, wvT, 1024, 1024);
    conv_t_k<<<dim3(32, 32), dim3(32, 8), 0, stream>>>(g1_w, nullptr, g1T, 1024, 1024);
    conv_t_k<<<dim3(32, 32), dim3(32, 8), 0, stream>>>(g2_w, nullptr, g2T, 1024, 1024);
    conv_t_k<<<dim3(2, 32),  dim3(32, 8), 0, stream>>>(fc2_w, nullptr, fc2T, 1024, 64);
    conv_t_k<<<dim3(4, 4),   dim3(32, 8), 0, stream>>>(wq2, wk2, wd2T, 128, 128);
    conv_t_k<<<dim3(4, 4),   dim3(32, 8), 0, stream>>>(gg1_w, nullptr, gg1T, 128, 128);
    conv_t_k<<<dim3(4, 4),   dim3(32, 8), 0, stream>>>(gg2_w, nullptr, gg2T, 128, 128);

    // x = features @ fc1_w + fc1_b
    gemm_bf16<0, __hip_bfloat16><<<dim3(8, 128), 256, 0, stream>>>(
        featb, fc1T, fc1_b, xb, 16384, 1024, 64, 0.f);

    // fused group chain -> e1 bf16 + cs1
    chain_k<<<1024, 256, 0, stream>>>(xb, wd2T, gg1T, gg2T, gg1_b, gg2_b, e1, cs1);

    // tail branch
    gemm_bf16<0, __hip_bfloat16><<<dim3(8, 16), 256, 0, stream>>>(
        xb + (size_t)14336 * 1024, wdT, nullptr, d2b, 2048, 1024, 1024, 0.f);
    gemm_bf16<1, __hip_bfloat16><<<dim3(8, 16), 256, 0, stream>>>(
        d2b, g1T, g1_b, t2b, 2048, 1024, 1024, 0.f);
    gemm_bf16<2, __hip_bfloat16><<<dim3(8, 16), 256, 0, stream>>>(
        t2b, g2T, g2_b, e2b, 2048, 1024, 1024, 0.03125f);
    colsum_bf_k<<<dim3(16, 8), dim3(64, 4), 0, stream>>>(e2b, cs2, 2048, 1024);

    // reciprocals (cs1, cs2 contiguous)
    rcs_k<<<8, 256, 0, stream>>>(cs1, 2048);

    // v-GEMM + fused res epilogue
    gemm_v_res<<<dim3(8, 128), 256, 0, stream>>>(
        xb, wvT, e1, e2b, cs1, cs2, invde, features, lpe, resb, 16384, 1024, 1024);

    // out = res @ fc2_w + fc2_b + features
    out_gemm_k<<<256, 256, 0, stream>>>(resb, fc2T, fc2_b, features, out);
}